// Round 1
// baseline (25.115 us; speedup 1.0000x reference)
//
#include <hip/hip_runtime.h>

// out[k] = sum_n sum_{i,j} frac[n,i]*frac[n,j]*cg[i,j,k]
// = sum_{i,j} M[i][j] * cg[i,j,k],  M = sum_n x x^T  (3x3 symmetric, 6 uniques)

constexpr int BLK  = 256;
constexpr int GRID = 2048;

__global__ __launch_bounds__(BLK) void tp_partial(const float* __restrict__ frac,
                                                  float* __restrict__ ws,
                                                  int nrows) {
    const float4* __restrict__ f4 = reinterpret_cast<const float4*>(frac);
    const int nquads = nrows >> 2;               // 4 rows = 12 floats = 3 float4
    const int tid    = blockIdx.x * BLK + threadIdx.x;
    const int stride = GRID * BLK;

    float s00 = 0.f, s01 = 0.f, s02 = 0.f, s11 = 0.f, s12 = 0.f, s22 = 0.f;

    for (int q = tid; q < nquads; q += stride) {
        const long base = 3L * q;
        float4 a = f4[base + 0];
        float4 b = f4[base + 1];
        float4 c = f4[base + 2];
        {   float x = a.x, y = a.y, z = a.z;
            s00 = fmaf(x, x, s00); s01 = fmaf(x, y, s01); s02 = fmaf(x, z, s02);
            s11 = fmaf(y, y, s11); s12 = fmaf(y, z, s12); s22 = fmaf(z, z, s22); }
        {   float x = a.w, y = b.x, z = b.y;
            s00 = fmaf(x, x, s00); s01 = fmaf(x, y, s01); s02 = fmaf(x, z, s02);
            s11 = fmaf(y, y, s11); s12 = fmaf(y, z, s12); s22 = fmaf(z, z, s22); }
        {   float x = b.z, y = b.w, z = c.x;
            s00 = fmaf(x, x, s00); s01 = fmaf(x, y, s01); s02 = fmaf(x, z, s02);
            s11 = fmaf(y, y, s11); s12 = fmaf(y, z, s12); s22 = fmaf(z, z, s22); }
        {   float x = c.y, y = c.z, z = c.w;
            s00 = fmaf(x, x, s00); s01 = fmaf(x, y, s01); s02 = fmaf(x, z, s02);
            s11 = fmaf(y, y, s11); s12 = fmaf(y, z, s12); s22 = fmaf(z, z, s22); }
    }

    // tail rows (nrows % 4), handled by one thread (none for N=2^23, safety only)
    if (tid == 0) {
        for (int r = (nquads << 2); r < nrows; ++r) {
            float x = frac[3L * r + 0], y = frac[3L * r + 1], z = frac[3L * r + 2];
            s00 += x * x; s01 += x * y; s02 += x * z;
            s11 += y * y; s12 += y * z; s22 += z * z;
        }
    }

    // wave (64-lane) butterfly reduction
    #pragma unroll
    for (int off = 32; off > 0; off >>= 1) {
        s00 += __shfl_down(s00, off);
        s01 += __shfl_down(s01, off);
        s02 += __shfl_down(s02, off);
        s11 += __shfl_down(s11, off);
        s12 += __shfl_down(s12, off);
        s22 += __shfl_down(s22, off);
    }

    __shared__ float red[BLK / 64][6];
    const int lane = threadIdx.x & 63;
    const int wave = threadIdx.x >> 6;
    if (lane == 0) {
        red[wave][0] = s00; red[wave][1] = s01; red[wave][2] = s02;
        red[wave][3] = s11; red[wave][4] = s12; red[wave][5] = s22;
    }
    __syncthreads();
    if (threadIdx.x < 6) {
        float v = red[0][threadIdx.x] + red[1][threadIdx.x]
                + red[2][threadIdx.x] + red[3][threadIdx.x];
        ws[blockIdx.x * 6 + threadIdx.x] = v;
    }
}

__global__ __launch_bounds__(BLK) void tp_final(const float* __restrict__ ws,
                                                const float* __restrict__ cg,
                                                float* __restrict__ out) {
    float s[6] = {0.f, 0.f, 0.f, 0.f, 0.f, 0.f};
    for (int b = threadIdx.x; b < GRID; b += BLK) {
        #pragma unroll
        for (int c = 0; c < 6; ++c) s[c] += ws[b * 6 + c];
    }
    #pragma unroll
    for (int off = 32; off > 0; off >>= 1) {
        #pragma unroll
        for (int c = 0; c < 6; ++c) s[c] += __shfl_down(s[c], off);
    }
    __shared__ float red[BLK / 64][6];
    const int lane = threadIdx.x & 63;
    const int wave = threadIdx.x >> 6;
    if (lane == 0) {
        #pragma unroll
        for (int c = 0; c < 6; ++c) red[wave][c] = s[c];
    }
    __syncthreads();

    __shared__ float M[9];   // full 3x3 from the 6 uniques
    if (threadIdx.x == 0) {
        float t[6];
        #pragma unroll
        for (int c = 0; c < 6; ++c)
            t[c] = red[0][c] + red[1][c] + red[2][c] + red[3][c];
        M[0] = t[0];  M[1] = t[1];  M[2] = t[2];   // (0,0) (0,1) (0,2)
        M[3] = t[1];  M[4] = t[3];  M[5] = t[4];   // (1,0) (1,1) (1,2)
        M[6] = t[2];  M[7] = t[4];  M[8] = t[5];   // (2,0) (2,1) (2,2)
    }
    __syncthreads();

    if (threadIdx.x < 9) {
        const int k = threadIdx.x;
        float acc = 0.f;
        #pragma unroll
        for (int p = 0; p < 9; ++p)
            acc = fmaf(M[p], cg[p * 9 + k], acc);   // cg[(i*3+j)*9 + k]
        out[k] = acc;
    }
}

extern "C" void kernel_launch(void* const* d_in, const int* in_sizes, int n_in,
                              void* d_out, int out_size, void* d_ws, size_t ws_size,
                              hipStream_t stream) {
    const float* frac = (const float*)d_in[0];       // [N, 3] flat
    const float* cg   = (const float*)d_in[1];       // [3, 3, 9] flat
    float*       out  = (float*)d_out;               // [9]
    float*       ws   = (float*)d_ws;                // GRID*6 floats = 48 KB

    const int nrows = in_sizes[0] / 3;

    tp_partial<<<GRID, BLK, 0, stream>>>(frac, ws, nrows);
    tp_final<<<1, BLK, 0, stream>>>(ws, cg, out);
}

// Round 2
// 23.299 us; speedup vs baseline: 1.0779x; 1.0779x over previous
//
#include <hip/hip_runtime.h>

// out[k] = sum_n sum_{i,j} frac[n,i]*frac[n,j]*cg[i,j,k]
//        = sum_{i,j} M[i][j] * cg[i,j,k],  M = sum_n x x^T (3x3 symmetric, 6 uniques)
//
// Pass 1: stream frac (96 MB), 8 rows = 6 float4 per thread per iteration,
//         block-reduce 6 uniques, write transposed partials ws[c][block].
// Pass 2: 1 block, coalesced float4 reads of ws, contract with cg -> out[9].

constexpr int BLK  = 256;
constexpr int GRID = 2048;   // 8 blocks/CU, 32 waves/CU

#define ACC6(x, y, z)                                              \
    do {                                                           \
        s00 = fmaf((x), (x), s00); s01 = fmaf((x), (y), s01);      \
        s02 = fmaf((x), (z), s02); s11 = fmaf((y), (y), s11);      \
        s12 = fmaf((y), (z), s12); s22 = fmaf((z), (z), s22);      \
    } while (0)

__global__ __launch_bounds__(BLK) void tp_partial(const float* __restrict__ frac,
                                                  float* __restrict__ ws,
                                                  int nrows) {
    const float4* __restrict__ f4 = reinterpret_cast<const float4*>(frac);
    const int noct   = nrows >> 3;                 // 8 rows = 24 floats = 6 float4
    const int tid    = blockIdx.x * BLK + threadIdx.x;
    const int stride = GRID * BLK;

    float s00 = 0.f, s01 = 0.f, s02 = 0.f, s11 = 0.f, s12 = 0.f, s22 = 0.f;

    #pragma unroll 2
    for (int g = tid; g < noct; g += stride) {
        const float4* __restrict__ p = f4 + 6L * g;
        float4 v0 = p[0], v1 = p[1], v2 = p[2];
        float4 v3 = p[3], v4 = p[4], v5 = p[5];
        ACC6(v0.x, v0.y, v0.z);
        ACC6(v0.w, v1.x, v1.y);
        ACC6(v1.z, v1.w, v2.x);
        ACC6(v2.y, v2.z, v2.w);
        ACC6(v3.x, v3.y, v3.z);
        ACC6(v3.w, v4.x, v4.y);
        ACC6(v4.z, v4.w, v5.x);
        ACC6(v5.y, v5.z, v5.w);
    }

    // tail rows (nrows % 8) — none for N=2^23, safety only
    if (blockIdx.x == 0 && threadIdx.x == 0) {
        for (int r = (noct << 3); r < nrows; ++r) {
            float x = frac[3L * r + 0], y = frac[3L * r + 1], z = frac[3L * r + 2];
            ACC6(x, y, z);
        }
    }

    // 64-lane butterfly reduction
    #pragma unroll
    for (int off = 32; off > 0; off >>= 1) {
        s00 += __shfl_down(s00, off);
        s01 += __shfl_down(s01, off);
        s02 += __shfl_down(s02, off);
        s11 += __shfl_down(s11, off);
        s12 += __shfl_down(s12, off);
        s22 += __shfl_down(s22, off);
    }

    __shared__ float red[BLK / 64][6];
    const int lane = threadIdx.x & 63;
    const int wave = threadIdx.x >> 6;
    if (lane == 0) {
        red[wave][0] = s00; red[wave][1] = s01; red[wave][2] = s02;
        red[wave][3] = s11; red[wave][4] = s12; red[wave][5] = s22;
    }
    __syncthreads();
    if (threadIdx.x < 6) {
        float v = red[0][threadIdx.x] + red[1][threadIdx.x]
                + red[2][threadIdx.x] + red[3][threadIdx.x];
        // transposed: ws[c][block] for coalesced pass-2 reads
        ws[threadIdx.x * GRID + blockIdx.x] = v;
    }
}

__global__ __launch_bounds__(BLK) void tp_final(const float* __restrict__ ws,
                                                const float* __restrict__ cg,
                                                float* __restrict__ out) {
    const float4* __restrict__ w4 = reinterpret_cast<const float4*>(ws); // [6][GRID/4]
    constexpr int Q = GRID / 4;   // 512 float4 per component

    float s[6];
    #pragma unroll
    for (int c = 0; c < 6; ++c) {
        float4 a = w4[c * Q + threadIdx.x];
        float4 b = w4[c * Q + threadIdx.x + BLK];
        s[c] = ((a.x + a.y) + (a.z + a.w)) + ((b.x + b.y) + (b.z + b.w));
    }

    #pragma unroll
    for (int off = 32; off > 0; off >>= 1) {
        #pragma unroll
        for (int c = 0; c < 6; ++c) s[c] += __shfl_down(s[c], off);
    }

    __shared__ float red[BLK / 64][6];
    const int lane = threadIdx.x & 63;
    const int wave = threadIdx.x >> 6;
    if (lane == 0) {
        #pragma unroll
        for (int c = 0; c < 6; ++c) red[wave][c] = s[c];
    }
    __syncthreads();

    __shared__ float M[9];   // full 3x3 from the 6 uniques
    if (threadIdx.x == 0) {
        float t[6];
        #pragma unroll
        for (int c = 0; c < 6; ++c)
            t[c] = red[0][c] + red[1][c] + red[2][c] + red[3][c];
        M[0] = t[0];  M[1] = t[1];  M[2] = t[2];
        M[3] = t[1];  M[4] = t[3];  M[5] = t[4];
        M[6] = t[2];  M[7] = t[4];  M[8] = t[5];
    }
    __syncthreads();

    if (threadIdx.x < 9) {
        const int k = threadIdx.x;
        float acc = 0.f;
        #pragma unroll
        for (int p = 0; p < 9; ++p)
            acc = fmaf(M[p], cg[p * 9 + k], acc);   // cg[(i*3+j)*9 + k]
        out[k] = acc;
    }
}

extern "C" void kernel_launch(void* const* d_in, const int* in_sizes, int n_in,
                              void* d_out, int out_size, void* d_ws, size_t ws_size,
                              hipStream_t stream) {
    const float* frac = (const float*)d_in[0];   // [N, 3] flat
    const float* cg   = (const float*)d_in[1];   // [3, 3, 9] flat
    float*       out  = (float*)d_out;           // [9]
    float*       ws   = (float*)d_ws;            // 6*GRID floats = 48 KB

    const int nrows = in_sizes[0] / 3;

    tp_partial<<<GRID, BLK, 0, stream>>>(frac, ws, nrows);
    tp_final<<<1, BLK, 0, stream>>>(ws, cg, out);
}